// Round 1
// 66.527 us; speedup vs baseline: 1.0328x; 1.0328x over previous
//
#include <hip/hip_runtime.h>
#include <math.h>

#define NUM_CLASSES 5
constexpr int B = 2, C = 64, D = 32, H = 64, W = 64;
constexpr int V = D * H * W;          // 131072
constexpr int TD = 16, TH = 32, TW = 32;
constexpr int TVOX = TD * TH * TW;    // 16384
constexpr float EPS_CENTER = 1e-6f;
constexpr float EPS_COS = 1e-8f;

// workspace layout (float offsets)
constexpr int OFF_SUMS_S = 0;                      // B*K*C = 640, layout [b][k][c]
constexpr int OFF_SUMS_T = 640;
constexpr int OFF_LOSS   = 1280;
constexpr int OFF_TICKET = 1281;                   // int
constexpr int OFF_CNT    = 1284;                   // 10 used
constexpr int WS_FLOATS  = 1312;

// prep: blocks 0..B-1 compute the label histogram (×8 for 2x2x2 upsample),
// blocks B.. zero the accumulator region. No LDS-atomic storm, no races:
// CNT region is store-written only by the histogram blocks.
__global__ void prep_kernel(const int* __restrict__ tgt, float* __restrict__ ws) {
    __shared__ int wred[4][NUM_CLASSES];
    const int tid = threadIdx.x;
    const int bid = blockIdx.x;
    if (bid < B) {
        int cnt[NUM_CLASSES] = {0, 0, 0, 0, 0};
        const int4* tp = reinterpret_cast<const int4*>(tgt + bid * TVOX);
#pragma unroll
        for (int i = 0; i < 16; ++i) {              // 16 int4 = 64 labels/thread
            int4 v = tp[tid + i * 256];
#pragma unroll
            for (int k = 0; k < NUM_CLASSES; ++k)
                cnt[k] += (v.x == k) + (v.y == k) + (v.z == k) + (v.w == k);
        }
        int lane = tid & 63, wid = tid >> 6;
#pragma unroll
        for (int k = 0; k < NUM_CLASSES; ++k) {
            int v = cnt[k];
            for (int off = 32; off; off >>= 1) v += __shfl_down(v, off);
            if (lane == 0) wred[wid][k] = v;
        }
        __syncthreads();
        if (tid < NUM_CLASSES)
            ws[OFF_CNT + bid * NUM_CLASSES + tid] =
                8.0f * (float)(wred[0][tid] + wred[1][tid] + wred[2][tid] + wred[3][tid]);
    } else {
        int i = (bid - B) * 256 + tid;
        if (i < OFF_TICKET + 1) ws[i] = 0.0f;       // sums + loss + ticket
    }
}

// per-(b,c) per-class sums for both tensors.
// grid: (16, B*C), 256 threads. Each block: one 8192-voxel chunk (2 z-planes,
// one tz label plane). Each thread: 8 float4 per tensor, 4 shared label int2s.
__global__ __launch_bounds__(256, 4) void sums_kernel(
    const float* __restrict__ fS, const float* __restrict__ fT,
    const int* __restrict__ tgt, float* __restrict__ ws)
{
    const int bc = blockIdx.y;           // 0..127
    const int b = bc >> 6, c = bc & 63;
    const int bx = blockIdx.x;           // 0..15 -> tz plane == bx
    const int tid = threadIdx.x;

    // labels: voxel positions u = tid*4 + i*1024 (i=0..7) within the chunk.
    //   x = (tid&15)*4 (const over i) -> tx pair = (tid&15)*2, +1
    //   y = (tid>>4) + 16*(i&3)       -> ty = (tid>>5) + 8*(i&3)
    //   z-local = i>>2               -> same tz for i and i+4
    const int* tb = tgt + b * TVOX + bx * (TH * TW) + (tid & 15) * 2;
    const int ty0 = tid >> 5;
    int2 L[4];
#pragma unroll
    for (int m = 0; m < 4; ++m)
        L[m] = *reinterpret_cast<const int2*>(tb + (ty0 + 8 * m) * TW);

    const float* baseS = fS + (long)bc * V + bx * 8192 + tid * 4;
    const float* baseT = fT + (long)bc * V + bx * 8192 + tid * 4;

    // issue ALL 16 float4 loads up front (max MLP; ~100 VGPRs, bounds allow 128)
    float4 sv[8], tv[8];
#pragma unroll
    for (int i = 0; i < 8; ++i) sv[i] = *reinterpret_cast<const float4*>(baseS + i * 1024);
#pragma unroll
    for (int i = 0; i < 8; ++i) tv[i] = *reinterpret_cast<const float4*>(baseT + i * 1024);

    float accS[NUM_CLASSES] = {0, 0, 0, 0, 0};
    float accT[NUM_CLASSES] = {0, 0, 0, 0, 0};
#pragma unroll
    for (int m = 0; m < 4; ++m) {
        // positions m and m+4 share the same label pair L[m]
        float s01 = (sv[m].x + sv[m].y) + (sv[m + 4].x + sv[m + 4].y);
        float s23 = (sv[m].z + sv[m].w) + (sv[m + 4].z + sv[m + 4].w);
        float t01 = (tv[m].x + tv[m].y) + (tv[m + 4].x + tv[m + 4].y);
        float t23 = (tv[m].z + tv[m].w) + (tv[m + 4].z + tv[m + 4].w);
        const int kx = L[m].x, ky = L[m].y;
#pragma unroll
        for (int k = 0; k < NUM_CLASSES; ++k) {     // static indices only
            float mx = (kx == k) ? 1.0f : 0.0f;
            float my = (ky == k) ? 1.0f : 0.0f;
            accS[k] += mx * s01 + my * s23;
            accT[k] += mx * t01 + my * t23;
        }
    }

    __shared__ float wsum[4][2 * NUM_CLASSES];
    int lane = tid & 63, wid = tid >> 6;
#pragma unroll
    for (int k = 0; k < NUM_CLASSES; ++k) {
        float vS = accS[k], vT = accT[k];
        for (int off = 32; off; off >>= 1) {
            vS += __shfl_down(vS, off);
            vT += __shfl_down(vT, off);
        }
        if (lane == 0) { wsum[wid][k] = vS; wsum[wid][NUM_CLASSES + k] = vT; }
    }
    __syncthreads();
    if (tid < 2 * NUM_CLASSES) {
        float v = wsum[0][tid] + wsum[1][tid] + wsum[2][tid] + wsum[3][tid];
        int k = tid % NUM_CLASSES;
        int dst = ((tid < NUM_CLASSES) ? OFF_SUMS_S : OFF_SUMS_T) + (b * NUM_CLASSES + k) * C + c;
        atomicAdd(&ws[dst], v);
    }
}

// per-voxel cosine (2 voxels/thread, shared label) + loss reduce + finalize.
// Means/norms computed per-block from the (L2-hot) sums — no means kernel.
// grid: (V/512, B), 256 threads.
__global__ __launch_bounds__(256) void loss_kernel(
    const float* __restrict__ fS, const float* __restrict__ fT,
    const int* __restrict__ tgt, float* __restrict__ ws, float* __restrict__ out)
{
    __shared__ float mST[C * NUM_CLASSES * 2];   // [c][k][{S,T}]
    __shared__ float nrm[2][8];
    __shared__ float red[4];
    int tid = threadIdx.x;
    int b = blockIdx.y;

    for (int i = tid; i < C * NUM_CLASSES; i += 256) {
        int c = i / NUM_CLASSES, k = i % NUM_CLASSES;
        float cnt = ws[OFF_CNT + b * NUM_CLASSES + k] + EPS_CENTER;
        mST[i * 2]     = ws[OFF_SUMS_S + (b * NUM_CLASSES + k) * C + c] / cnt;
        mST[i * 2 + 1] = ws[OFF_SUMS_T + (b * NUM_CLASSES + k) * C + c] / cnt;
    }
    __syncthreads();
    if (tid < 2 * NUM_CLASSES) {                 // 10 center norms
        int k = tid % NUM_CLASSES;
        int st = tid / NUM_CLASSES;              // 0=S, 1=T
        float s = 0.0f;
        for (int c = 0; c < C; ++c) { float v = mST[(c * NUM_CLASSES + k) * 2 + st]; s += v * v; }
        nrm[st][k] = sqrtf(s);
    }
    __syncthreads();

    int v = (blockIdx.x * 256 + tid) * 2;        // even voxel pair
    int z = v >> 12, y = (v >> 6) & 63, x = v & 63;
    int k = tgt[b * TVOX + (z >> 1) * (TH * TW) + (y >> 1) * TW + (x >> 1)];

    const float* pS = fS + (long)b * C * V + v;
    const float* pT = fT + (long)b * C * V + v;
    float d0S = 0, d1S = 0, q0S = 0, q1S = 0;
    float d0T = 0, d1T = 0, q0T = 0, q1T = 0;
#pragma unroll 8
    for (int c = 0; c < C; ++c) {
        float2 a = *reinterpret_cast<const float2*>(pS + (long)c * V);
        float2 t = *reinterpret_cast<const float2*>(pT + (long)c * V);
        float2 m = *reinterpret_cast<const float2*>(&mST[(c * NUM_CLASSES + k) * 2]);
        d0S += a.x * m.x; d1S += a.y * m.x; q0S += a.x * a.x; q1S += a.y * a.y;
        d0T += t.x * m.y; d1T += t.y * m.y; q0T += t.x * t.x; q1T += t.y * t.y;
    }
    float c0S = d0S / fmaxf(sqrtf(q0S) * nrm[0][k], EPS_COS);
    float c1S = d1S / fmaxf(sqrtf(q1S) * nrm[0][k], EPS_COS);
    float c0T = d0T / fmaxf(sqrtf(q0T) * nrm[1][k], EPS_COS);
    float c1T = d1T / fmaxf(sqrtf(q1T) * nrm[1][k], EPS_COS);
    float e0 = c0S - c0T, e1 = c1S - c1T;
    float val = e0 * e0 + e1 * e1;

    for (int off = 32; off; off >>= 1) val += __shfl_down(val, off);
    int lane = tid & 63, wid = tid >> 6;
    if (lane == 0) red[wid] = val;
    __syncthreads();
    if (tid == 0) {
        atomicAdd(&ws[OFF_LOSS], red[0] + red[1] + red[2] + red[3]);
        __threadfence();
        int prev = atomicAdd(reinterpret_cast<int*>(ws) + OFF_TICKET, 1);
        if (prev == (int)(gridDim.x * gridDim.y) - 1) {
            float total = atomicAdd(&ws[OFF_LOSS], 0.0f);   // coherent read
            out[0] = total * (1.0f / (float)(B * V));
        }
    }
}

extern "C" void kernel_launch(void* const* d_in, const int* in_sizes, int n_in,
                              void* d_out, int out_size, void* d_ws, size_t ws_size,
                              hipStream_t stream) {
    const float* fS  = (const float*)d_in[0];
    const float* fT  = (const float*)d_in[1];
    const int*   tgt = (const int*)d_in[2];
    float* out = (float*)d_out;
    float* ws  = (float*)d_ws;

    prep_kernel<<<dim3(B + 6), 256, 0, stream>>>(tgt, ws);
    sums_kernel<<<dim3(16, B * C), 256, 0, stream>>>(fS, fT, tgt, ws);
    loss_kernel<<<dim3(V / 512, B), 256, 0, stream>>>(fS, fT, tgt, ws, out);
}